// Round 7
// baseline (177.898 us; speedup 1.0000x reference)
//
#include <hip/hip_runtime.h>
#include <hip/hip_bf16.h>

// GCN forward, algebraically collapsed (no nonlinearity between convs, mean pool):
//   g = (1/n)*((A^T u)^T X)@W1@W2 + (1/n)*(sum u)*(b1@W2) + b2,  A = D^-1/2(Adj+I)D^-1/2
// Round 7: scatter = 256 blocks (128 slices x 2 ranges) so ALL CUs are busy
// (round 6's 128-block scatter idled half the chip); fold(2)+feature pass
// fused into k_tail (tile-owned wv in LDS, no global round-trip); ctr memset
// folded into scatter-0. 6 dispatches total.

#define D_IN 128
#define D_HID 256
#define D_DENSE 128
#define R0 10240          // range-0 bins (40 KB LDS)
#define NSL 128           // edge slices == replicas per range
#define NFOLD 250         // fold blocks (FOLD_C nodes each)
#define FOLD_C 80
#define NTILE 157         // ceil(20000/128) k_tail tiles

// ---- edge scatter: block = (slice, range); LDS histogram of own range -----
// mode 0: bin[col[e]] += w[e]
// mode 1: bin[row[e]] += w[e]*dinv[col[e]]
// mode 2: bin[row[e]] += w[e]*dinv[col[e]]*u[col[e]]
__global__ __launch_bounds__(1024) void k_scatter(
    const int* __restrict__ tgt, const int* __restrict__ src,
    const float* __restrict__ w, const float* __restrict__ dinv,
    const float* __restrict__ u, float* __restrict__ part,
    unsigned* __restrict__ ctr, int E, int N, int mode) {
    __shared__ float acc[R0];
    if (mode == 0 && blockIdx.x == 0 && threadIdx.x == 0) ctr[0] = 0u;
    const int range = blockIdx.x & 1;
    const int slice = blockIdx.x >> 1;           // 0..NSL-1
    const int base  = range ? R0 : 0;
    const int lim   = range ? (N - R0) : R0;
    const int per = (E + NSL - 1) / NSL;         // 5000
    const int e0 = slice * per, e1 = min(e0 + per, E);
    float* outp = part + (range ? (size_t)NSL * R0 + (size_t)slice * lim
                                : (size_t)slice * lim);
    for (int i = threadIdx.x; i < lim; i += 1024) acc[i] = 0.f;
    __syncthreads();
    for (int e = e0 + threadIdx.x; e < e1; e += 1024) {
        int t = tgt[e] - base;
        if ((unsigned)t < (unsigned)lim) {
            float v = w[e];
            if (mode != 0) {
                int c = src[e];
                float dc = dinv[c];
                v *= (mode == 2) ? dc * u[c] : dc;
            }
            atomicAdd(&acc[t], v);               // LDS atomic
        }
    }
    __syncthreads();
    for (int i = threadIdx.x; i < lim; i += 1024) outp[i] = acc[i];
}

// ---- fold 128 replicas + node math (modes 0,1); mode-0 spare blocks: M=W1@W2
__global__ __launch_bounds__(1024) void k_fold(
    const float* __restrict__ part, float* __restrict__ dinv,
    float* __restrict__ u, float* __restrict__ S_u_part,
    const float* __restrict__ W1, const float* __restrict__ b1,
    const float* __restrict__ W2, float* __restrict__ M, float* __restrict__ c2,
    int N, int mode) {
    __shared__ float lds[1044];
    const int b = blockIdx.x, tid = threadIdx.x;

    if (b >= NFOLD) {                            // ---- M / c2 precompute ----
        int q = b - NFOLD;                       // 0..63: 4 cols of M each
        lds[tid] = W2[(tid >> 2) * 256 + q * 4 + (tid & 3)];
        __syncthreads();
        int wvi = tid >> 6, lane = tid & 63;
        for (int kr = 0; kr < 8; ++kr) {
            int k = wvi * 8 + kr;                // 16 waves x 8 = 128 rows
            float a0 = 0, a1 = 0, a2 = 0, a3 = 0;
            #pragma unroll
            for (int it = 0; it < 4; ++it) {
                int j = it * 64 + lane;
                float a = W1[k * 256 + j];
                a0 += a * lds[j*4+0]; a1 += a * lds[j*4+1];
                a2 += a * lds[j*4+2]; a3 += a * lds[j*4+3];
            }
            #pragma unroll
            for (int off = 32; off > 0; off >>= 1) {
                a0 += __shfl_down(a0, off, 64); a1 += __shfl_down(a1, off, 64);
                a2 += __shfl_down(a2, off, 64); a3 += __shfl_down(a3, off, 64);
            }
            if (lane == 0) {
                M[k * 256 + q*4 + 0] = a0; M[k * 256 + q*4 + 1] = a1;
                M[k * 256 + q*4 + 2] = a2; M[k * 256 + q*4 + 3] = a3;
            }
        }
        if (wvi == 0) {                          // c2 = b1 @ W2 slab
            float a0 = 0, a1 = 0, a2 = 0, a3 = 0;
            #pragma unroll
            for (int it = 0; it < 4; ++it) {
                int j = it * 64 + lane;
                float a = b1[j];
                a0 += a * lds[j*4+0]; a1 += a * lds[j*4+1];
                a2 += a * lds[j*4+2]; a3 += a * lds[j*4+3];
            }
            #pragma unroll
            for (int off = 32; off > 0; off >>= 1) {
                a0 += __shfl_down(a0, off, 64); a1 += __shfl_down(a1, off, 64);
                a2 += __shfl_down(a2, off, 64); a3 += __shfl_down(a3, off, 64);
            }
            if (lane == 0) {
                c2[q*4+0] = a0; c2[q*4+1] = a1;
                c2[q*4+2] = a2; c2[q*4+3] = a3;
            }
        }
        return;
    }

    // ---- replica fold: 80 nodes/block, 8 rgroups x 16 replicas ------------
    const int j = tid & 127, rg = tid >> 7;
    const int i = b * FOLD_C + j;                // boundary at b=128 == R0 exactly
    const bool act = (j < FOLD_C) && (i < N);
    float sv = 0.f;
    if (act) {
        size_t st; const float* pp;
        if (i < R0) { st = R0;            pp = part + i; }
        else        { st = (size_t)(N - R0); pp = part + (size_t)NSL * R0 + (i - R0); }
        pp += (size_t)rg * 16 * st;
        #pragma unroll
        for (int r = 0; r < 16; ++r) sv += pp[(size_t)r * st];
    }
    lds[rg * 128 + j] = sv;
    __syncthreads();
    float ui = 0.f;
    if (rg == 0) {
        float tot = 0.f;
        #pragma unroll
        for (int q = 0; q < 8; ++q) tot += lds[q * 128 + j];
        if (act) {
            if (mode == 0) dinv[i] = rsqrtf(tot + 1.0f);          // +1 self-loop
            else { float d = dinv[i]; ui = d * (tot + d); u[i] = ui; }
        }
    }
    if (mode == 1) {                             // S_u partial per block
        float v = ui;
        #pragma unroll
        for (int off = 32; off > 0; off >>= 1) v += __shfl_down(v, off, 64);
        if ((tid & 63) == 0) lds[1028 + (tid >> 6)] = v;
        __syncthreads();
        if (tid == 0) {
            float t2 = 0.f;
            #pragma unroll
            for (int q = 0; q < 16; ++q) t2 += lds[1028 + q];
            S_u_part[b] = t2;
        }
    }
}

// ---- barrier helpers (device-scope counter in d_ws) ------------------------
__device__ __forceinline__ void g_arrive(unsigned* ctr) {
    __syncthreads();
    if (threadIdx.x == 0)
        __hip_atomic_fetch_add(ctr, 1u, __ATOMIC_RELEASE, __HIP_MEMORY_SCOPE_AGENT);
}
__device__ __forceinline__ void g_wait(unsigned* ctr, unsigned target) {
    if (threadIdx.x == 0) {
        while (__hip_atomic_load(ctr, __ATOMIC_ACQUIRE, __HIP_MEMORY_SCOPE_AGENT) < target)
            __builtin_amdgcn_s_sleep(2);
    }
    __syncthreads();
}

// ---- tail: fold wv (tile-owned) + feature contraction + head ---------------
// 256 blocks x 256 threads, co-resident. Counter targets: 256 / 272 / 288.
__global__ __launch_bounds__(256) void k_tail(
    const float* __restrict__ x, const float* __restrict__ part,
    const float* __restrict__ dinv, const float* __restrict__ u,
    const float* __restrict__ S_u_part, const float* __restrict__ M,
    const float* __restrict__ c2, const float* __restrict__ b2,
    const float* __restrict__ Wd1, const float* __restrict__ bd1,
    const float* __restrict__ Wd2, const float* __restrict__ bd2,
    float* __restrict__ s_part, float* __restrict__ g_part,
    float* __restrict__ z_part, float* __restrict__ S_u_g,
    unsigned* __restrict__ ctr, float* __restrict__ out,
    int N, float inv_n) {
    __shared__ float sh[256];
    __shared__ float wvl[128];
    __shared__ float ss[128];
    __shared__ float gv[16];
    __shared__ float su4[4];
    const int b = blockIdx.x, tid = threadIdx.x;
    const int k = tid & 127, rg = tid >> 7;

    // ---- phase A: fold wv for tile b (128 nodes), contract against x ------
    if (b < NTILE) {
        const int i0 = b * 128;                  // tile 80 starts at R0 exactly
        const int i = i0 + k;
        const bool act = i < N;
        float sv = 0.f;
        if (act) {
            size_t st; const float* pp;
            if (i < R0) { st = R0;               pp = part + i; }
            else        { st = (size_t)(N - R0); pp = part + (size_t)NSL * R0 + (i - R0); }
            pp += (size_t)rg * 64 * st;
            #pragma unroll 16
            for (int r = 0; r < 64; ++r) sv += pp[(size_t)r * st];
        }
        sh[tid] = sv;
        __syncthreads();
        if (rg == 0) {
            float q = sh[k] + sh[128 + k];
            float d = act ? dinv[i] : 0.f;
            wvl[k] = act ? d * (q + d * u[i]) : 0.f;   // wv = dinv*(q + dinv*u)
        }
        __syncthreads();
        float acc = 0.f;
        for (int m = rg; m < 128; m += 2) {
            int i2 = i0 + m;
            if (i2 >= N) break;
            acc += wvl[m] * x[(size_t)i2 * D_IN + k];
        }
        sh[tid] = acc;
        __syncthreads();
        if (rg == 0) s_part[b * 128 + k] = sh[k] + sh[128 + k];
    }
    g_arrive(ctr);
    if (b >= 16) return;
    g_wait(ctr, 256);

    // ---- phase B: fold s + S_u; g_part[b][t] from M rows [8b,8b+8) --------
    {
        float a2 = 0.f;
        for (int q = rg; q < NTILE; q += 2) a2 += s_part[q * 128 + k];
        sh[tid] = a2;
        float v = 0.f;
        if (b == 0) {
            v = (tid < NFOLD) ? S_u_part[tid] : 0.f;
            #pragma unroll
            for (int off = 32; off > 0; off >>= 1) v += __shfl_down(v, off, 64);
        }
        __syncthreads();
        if (rg == 0) ss[k] = sh[k] + sh[128 + k];         // s[k]
        if (b == 0 && (tid & 63) == 0) su4[tid >> 6] = v;
        __syncthreads();
        if (b == 0 && tid == 0) S_u_g[0] = su4[0] + su4[1] + su4[2] + su4[3];
        float gp = 0.f;
        #pragma unroll
        for (int kk = 0; kk < 8; ++kk)
            gp += ss[b * 8 + kk] * M[(b * 8 + kk) * 256 + tid];
        g_part[b * 256 + tid] = gp;
    }
    g_arrive(ctr);
    g_wait(ctr, 272);

    // ---- phase C: fold g slice [16b,16b+16); z_part[b][t<128] -------------
    {
        if (tid < 16) {
            int kk = b * 16 + tid;
            float gval = 0.f;
            #pragma unroll
            for (int p2 = 0; p2 < 16; ++p2) gval += g_part[p2 * 256 + kk];
            gv[tid] = (gval + S_u_g[0] * c2[kk]) * inv_n + b2[kk];
        }
        __syncthreads();
        if (tid < 128) {
            float z = 0.f;
            #pragma unroll
            for (int kk = 0; kk < 16; ++kk)
                z += gv[kk] * Wd1[(b * 16 + kk) * D_DENSE + tid];
            z_part[b * 128 + tid] = z;
        }
    }
    g_arrive(ctr);
    if (b != 0) return;
    g_wait(ctr, 288);

    // ---- phase D: fold z, relu, logits, softmax (block 0) -----------------
    float p0 = 0.f, p1 = 0.f;
    if (tid < 128) {
        float zr = bd1[tid];
        #pragma unroll
        for (int p2 = 0; p2 < 16; ++p2) zr += z_part[p2 * 128 + tid];
        float zt = fmaxf(zr, 0.f);
        p0 = zt * Wd2[tid * 2 + 0];
        p1 = zt * Wd2[tid * 2 + 1];
    }
    #pragma unroll
    for (int off = 32; off > 0; off >>= 1) {
        p0 += __shfl_down(p0, off, 64);
        p1 += __shfl_down(p1, off, 64);
    }
    if ((tid & 63) == 0) { sh[tid >> 6] = p0; sh[16 + (tid >> 6)] = p1; }
    __syncthreads();
    if (tid == 0) {
        float l0 = sh[0] + sh[1] + sh[2] + sh[3] + bd2[0];
        float l1 = sh[16] + sh[17] + sh[18] + sh[19] + bd2[1];
        float m = fmaxf(l0, l1);
        float e0 = expf(l0 - m), e1 = expf(l1 - m);
        float inv = 1.0f / (e0 + e1);
        out[0] = e0 * inv;
        out[1] = e1 * inv;
    }
}

extern "C" void kernel_launch(void* const* d_in, const int* in_sizes, int n_in,
                              void* d_out, int out_size, void* d_ws, size_t ws_size,
                              hipStream_t stream) {
    const float* x   = (const float*)d_in[0];
    const int*   ei  = (const int*)  d_in[1];
    const float* w   = (const float*)d_in[2];
    const float* W1  = (const float*)d_in[3];
    const float* b1  = (const float*)d_in[4];
    const float* W2  = (const float*)d_in[5];
    const float* b2  = (const float*)d_in[6];
    const float* Wd1 = (const float*)d_in[7];
    const float* bd1 = (const float*)d_in[8];
    const float* Wd2 = (const float*)d_in[9];
    const float* bd2 = (const float*)d_in[10];
    float* out = (float*)d_out;

    const int N = in_sizes[0] / D_IN;      // 20000
    const int E = in_sizes[1] / 2;         // 640000
    const int* row = ei;
    const int* col = ei + E;

    // workspace layout. Everything except ctr is written before read; ctr is
    // zeroed by scatter-0 (two kernel boundaries before k_tail reads it).
    unsigned* ctr = (unsigned*)d_ws;                       // 16 slots
    float* fws    = (float*)d_ws + 16;
    float* part   = fws;                                   // NSL*N = 2.56M
    float* dinv   = part + (size_t)NSL * N;                // N
    float* u      = dinv + N;                              // N
    float* s_part = u + N;                                 // NTILE*128
    float* S_u_p  = s_part + (size_t)NTILE * D_IN;         // NFOLD
    float* S_u_g  = S_u_p + NFOLD;                         // 1
    float* M      = S_u_g + 1;                             // 128*256
    float* c2     = M + D_IN * D_HID;                      // 256
    float* g_part = c2 + D_HID;                            // 16*256
    float* z_part = g_part + 16 * D_HID;                   // 16*128

    // pass 1: deg by col -> dinv; spare fold blocks compute M=W1@W2, c2=b1@W2
    k_scatter<<<2 * NSL, 1024, 0, stream>>>(col, row, w, dinv, u, part, ctr, E, N, 0);
    k_fold<<<NFOLD + 64, 1024, 0, stream>>>(part, dinv, u, S_u_p, W1, b1, W2, M, c2, N, 0);
    // pass 2: by row, gather dinv[col] -> u, S_u partials
    k_scatter<<<2 * NSL, 1024, 0, stream>>>(row, col, w, dinv, u, part, ctr, E, N, 1);
    k_fold<<<NFOLD, 1024, 0, stream>>>(part, dinv, u, S_u_p, W1, b1, W2, M, c2, N, 1);
    // pass 3: by row, gather dinv[col]*u[col] -> (folded inside k_tail)
    k_scatter<<<2 * NSL, 1024, 0, stream>>>(row, col, w, dinv, u, part, ctr, E, N, 2);
    // wv-fold + feature contraction + head (light device barriers inside)
    k_tail<<<256, 256, 0, stream>>>(x, part, dinv, u, S_u_p, M, c2, b2,
                                    Wd1, bd1, Wd2, bd2, s_part, g_part, z_part,
                                    S_u_g, ctr, out, N, 1.0f / (float)N);
}

// Round 8
// 149.941 us; speedup vs baseline: 1.1865x; 1.1865x over previous
//
#include <hip/hip_runtime.h>
#include <hip/hip_bf16.h>

// GCN forward, algebraically collapsed (no nonlinearity between convs, mean pool):
//   g = (1/n)*((A^T u)^T X)@W1@W2 + (1/n)*(sum u)*(b1@W2) + b2,  A = D^-1/2(Adj+I)D^-1/2
// Round 8: k_tail rebuilt at 1024 thr/block (16 waves/CU vs 4) with fixed-bound
// fully-unrolled fold/contraction loops — round 7's k_tail was latency-starved
// (63us, VALUBusy 1.2%: 64-iteration non-pipelined loops at 4 waves/CU).

#define D_IN 128
#define D_HID 256
#define D_DENSE 128
#define R0 10240          // range-0 bins (40 KB LDS)
#define NSL 128           // edge slices == replicas per range
#define NFOLD 250         // fold blocks (FOLD_C nodes each)
#define FOLD_C 80
#define NTILE 157         // ceil(20000/128) k_tail tiles

// ---- edge scatter: block = (slice, range); LDS histogram of own range -----
// mode 0: bin[col[e]] += w[e]
// mode 1: bin[row[e]] += w[e]*dinv[col[e]]
// mode 2: bin[row[e]] += w[e]*dinv[col[e]]*u[col[e]]
__global__ __launch_bounds__(1024) void k_scatter(
    const int* __restrict__ tgt, const int* __restrict__ src,
    const float* __restrict__ w, const float* __restrict__ dinv,
    const float* __restrict__ u, float* __restrict__ part,
    unsigned* __restrict__ ctr, int E, int N, int mode) {
    __shared__ float acc[R0];
    if (mode == 0 && blockIdx.x == 0 && threadIdx.x == 0) ctr[0] = 0u;
    const int range = blockIdx.x & 1;
    const int slice = blockIdx.x >> 1;           // 0..NSL-1
    const int base  = range ? R0 : 0;
    const int lim   = range ? (N - R0) : R0;
    const int per = (E + NSL - 1) / NSL;         // 5000
    const int e0 = slice * per, e1 = min(e0 + per, E);
    float* outp = part + (range ? (size_t)NSL * R0 + (size_t)slice * lim
                                : (size_t)slice * lim);
    for (int i = threadIdx.x; i < lim; i += 1024) acc[i] = 0.f;
    __syncthreads();
    for (int e = e0 + threadIdx.x; e < e1; e += 1024) {
        int t = tgt[e] - base;
        if ((unsigned)t < (unsigned)lim) {
            float v = w[e];
            if (mode != 0) {
                int c = src[e];
                float dc = dinv[c];
                v *= (mode == 2) ? dc * u[c] : dc;
            }
            atomicAdd(&acc[t], v);               // LDS atomic
        }
    }
    __syncthreads();
    for (int i = threadIdx.x; i < lim; i += 1024) outp[i] = acc[i];
}

// ---- fold 128 replicas + node math (modes 0,1); mode-0 spare blocks: M=W1@W2
__global__ __launch_bounds__(1024) void k_fold(
    const float* __restrict__ part, float* __restrict__ dinv,
    float* __restrict__ u, float* __restrict__ S_u_part,
    const float* __restrict__ W1, const float* __restrict__ b1,
    const float* __restrict__ W2, float* __restrict__ M, float* __restrict__ c2,
    int N, int mode) {
    __shared__ float lds[1044];
    const int b = blockIdx.x, tid = threadIdx.x;

    if (b >= NFOLD) {                            // ---- M / c2 precompute ----
        int q = b - NFOLD;                       // 0..63: 4 cols of M each
        lds[tid] = W2[(tid >> 2) * 256 + q * 4 + (tid & 3)];
        __syncthreads();
        int wvi = tid >> 6, lane = tid & 63;
        for (int kr = 0; kr < 8; ++kr) {
            int k = wvi * 8 + kr;                // 16 waves x 8 = 128 rows
            float a0 = 0, a1 = 0, a2 = 0, a3 = 0;
            #pragma unroll
            for (int it = 0; it < 4; ++it) {
                int j = it * 64 + lane;
                float a = W1[k * 256 + j];
                a0 += a * lds[j*4+0]; a1 += a * lds[j*4+1];
                a2 += a * lds[j*4+2]; a3 += a * lds[j*4+3];
            }
            #pragma unroll
            for (int off = 32; off > 0; off >>= 1) {
                a0 += __shfl_down(a0, off, 64); a1 += __shfl_down(a1, off, 64);
                a2 += __shfl_down(a2, off, 64); a3 += __shfl_down(a3, off, 64);
            }
            if (lane == 0) {
                M[k * 256 + q*4 + 0] = a0; M[k * 256 + q*4 + 1] = a1;
                M[k * 256 + q*4 + 2] = a2; M[k * 256 + q*4 + 3] = a3;
            }
        }
        if (wvi == 0) {                          // c2 = b1 @ W2 slab
            float a0 = 0, a1 = 0, a2 = 0, a3 = 0;
            #pragma unroll
            for (int it = 0; it < 4; ++it) {
                int j = it * 64 + lane;
                float a = b1[j];
                a0 += a * lds[j*4+0]; a1 += a * lds[j*4+1];
                a2 += a * lds[j*4+2]; a3 += a * lds[j*4+3];
            }
            #pragma unroll
            for (int off = 32; off > 0; off >>= 1) {
                a0 += __shfl_down(a0, off, 64); a1 += __shfl_down(a1, off, 64);
                a2 += __shfl_down(a2, off, 64); a3 += __shfl_down(a3, off, 64);
            }
            if (lane == 0) {
                c2[q*4+0] = a0; c2[q*4+1] = a1;
                c2[q*4+2] = a2; c2[q*4+3] = a3;
            }
        }
        return;
    }

    // ---- replica fold: 80 nodes/block, 8 rgroups x 16 replicas ------------
    const int j = tid & 127, rg = tid >> 7;
    const int i = b * FOLD_C + j;
    const bool act = (j < FOLD_C) && (i < N);
    float sv = 0.f;
    if (act) {
        size_t st; const float* pp;
        if (i < R0) { st = R0;               pp = part + i; }
        else        { st = (size_t)(N - R0); pp = part + (size_t)NSL * R0 + (i - R0); }
        pp += (size_t)rg * 16 * st;
        #pragma unroll
        for (int r = 0; r < 16; ++r) sv += pp[(size_t)r * st];
    }
    lds[rg * 128 + j] = sv;
    __syncthreads();
    float ui = 0.f;
    if (rg == 0) {
        float tot = 0.f;
        #pragma unroll
        for (int q = 0; q < 8; ++q) tot += lds[q * 128 + j];
        if (act) {
            if (mode == 0) dinv[i] = rsqrtf(tot + 1.0f);          // +1 self-loop
            else { float d = dinv[i]; ui = d * (tot + d); u[i] = ui; }
        }
    }
    if (mode == 1) {                             // S_u partial per block
        float v = ui;
        #pragma unroll
        for (int off = 32; off > 0; off >>= 1) v += __shfl_down(v, off, 64);
        if ((tid & 63) == 0) lds[1028 + (tid >> 6)] = v;
        __syncthreads();
        if (tid == 0) {
            float t2 = 0.f;
            #pragma unroll
            for (int q = 0; q < 16; ++q) t2 += lds[1028 + q];
            S_u_part[b] = t2;
        }
    }
}

// ---- barrier helpers (device-scope counter in d_ws) ------------------------
__device__ __forceinline__ void g_arrive(unsigned* ctr) {
    __syncthreads();
    if (threadIdx.x == 0)
        __hip_atomic_fetch_add(ctr, 1u, __ATOMIC_RELEASE, __HIP_MEMORY_SCOPE_AGENT);
}
__device__ __forceinline__ void g_wait(unsigned* ctr, unsigned target) {
    if (threadIdx.x == 0) {
        while (__hip_atomic_load(ctr, __ATOMIC_ACQUIRE, __HIP_MEMORY_SCOPE_AGENT) < target)
            __builtin_amdgcn_s_sleep(2);
    }
    __syncthreads();
}

// ---- tail: fold wv (tile-owned) + feature contraction + head ---------------
// 256 blocks x 1024 threads (16 waves/CU), co-resident. Targets: 256/272/288.
__global__ __launch_bounds__(1024) void k_tail(
    const float* __restrict__ x, const float* __restrict__ part,
    const float* __restrict__ dinv, const float* __restrict__ u,
    const float* __restrict__ S_u_part, const float* __restrict__ M,
    const float* __restrict__ c2, const float* __restrict__ b2,
    const float* __restrict__ Wd1, const float* __restrict__ bd1,
    const float* __restrict__ Wd2, const float* __restrict__ bd2,
    float* __restrict__ s_part, float* __restrict__ g_part,
    float* __restrict__ z_part, float* __restrict__ S_u_g,
    unsigned* __restrict__ ctr, float* __restrict__ out,
    int N, float inv_n) {
    __shared__ float sh[1024];
    __shared__ float wvl[128];
    __shared__ float ss[128];
    __shared__ float gv[16];
    __shared__ float su[16];
    const int b = blockIdx.x, tid = threadIdx.x;
    const int k = tid & 127, rg = tid >> 7;      // rg in [0,8)

    // ---- phase A: fold wv for tile b (128 nodes), contract against x ------
    if (b < NTILE) {
        const int i0 = b * 128;
        const int i = i0 + k;
        const bool act = i < N;
        // replica fold: 16 strided loads/thread, one outstanding batch
        float sv = 0.f;
        if (act) {
            size_t st; const float* pp;
            if (i < R0) { st = R0;               pp = part + i; }
            else        { st = (size_t)(N - R0); pp = part + (size_t)NSL * R0 + (i - R0); }
            pp += (size_t)rg * 16 * st;
            #pragma unroll
            for (int r = 0; r < 16; ++r) sv += pp[(size_t)r * st];
        }
        sh[tid] = sv;
        __syncthreads();
        if (rg == 0) {
            float q = 0.f;
            #pragma unroll
            for (int t2 = 0; t2 < 8; ++t2) q += sh[t2 * 128 + k];
            float d = act ? dinv[i] : 0.f;
            wvl[k] = act ? d * (q + d * u[i]) : 0.f;   // wv = dinv*(q + dinv*u)
        }
        __syncthreads();
        // contraction: 16 unrolled rows/thread, index clamped (wvl==0 masks)
        float acc = 0.f;
        #pragma unroll
        for (int jj = 0; jj < 16; ++jj) {
            int m = rg + 8 * jj;
            int i2 = i0 + m;
            float xv = x[(size_t)(i2 < N ? i2 : i0) * D_IN + k];
            acc += wvl[m] * xv;
        }
        sh[tid] = acc;
        __syncthreads();
        if (rg == 0) {
            float t2s = 0.f;
            #pragma unroll
            for (int t2 = 0; t2 < 8; ++t2) t2s += sh[t2 * 128 + k];
            s_part[b * 128 + k] = t2s;
        }
    }
    g_arrive(ctr);
    if (b >= 16) return;
    g_wait(ctr, 256);

    // ---- phase B: fold s + S_u; g_part[b][t] from M rows [8b,8b+8) --------
    {
        float a2 = 0.f;
        for (int q = rg; q < NTILE; q += 8) a2 += s_part[q * 128 + k];
        sh[tid] = a2;
        float v = 0.f;
        if (b == 0) {
            v = (tid < NFOLD) ? S_u_part[tid] : 0.f;
            #pragma unroll
            for (int off = 32; off > 0; off >>= 1) v += __shfl_down(v, off, 64);
        }
        __syncthreads();
        if (rg == 0) {
            float t2 = 0.f;
            #pragma unroll
            for (int q = 0; q < 8; ++q) t2 += sh[q * 128 + k];
            ss[k] = t2;                                   // s[k]
        }
        if (b == 0 && (tid & 63) == 0) su[tid >> 6] = v;
        __syncthreads();
        if (b == 0 && tid == 0) {
            float t2 = 0.f;
            #pragma unroll
            for (int q = 0; q < 16; ++q) t2 += su[q];
            S_u_g[0] = t2;
        }
        if (tid < 256) {
            float gp = 0.f;
            #pragma unroll
            for (int kk = 0; kk < 8; ++kk)
                gp += ss[b * 8 + kk] * M[(b * 8 + kk) * 256 + tid];
            g_part[b * 256 + tid] = gp;
        }
    }
    g_arrive(ctr);
    g_wait(ctr, 272);

    // ---- phase C: fold g slice [16b,16b+16); z_part[b][t<128] -------------
    {
        if (tid < 16) {
            int kk = b * 16 + tid;
            float gval = 0.f;
            #pragma unroll
            for (int p2 = 0; p2 < 16; ++p2) gval += g_part[p2 * 256 + kk];
            gv[tid] = (gval + S_u_g[0] * c2[kk]) * inv_n + b2[kk];
        }
        __syncthreads();
        if (tid < 128) {
            float z = 0.f;
            #pragma unroll
            for (int kk = 0; kk < 16; ++kk)
                z += gv[kk] * Wd1[(b * 16 + kk) * D_DENSE + tid];
            z_part[b * 128 + tid] = z;
        }
    }
    g_arrive(ctr);
    if (b != 0) return;
    g_wait(ctr, 288);

    // ---- phase D: fold z, relu, logits, softmax (block 0) -----------------
    float p0 = 0.f, p1 = 0.f;
    if (tid < 128) {
        float zr = bd1[tid];
        #pragma unroll
        for (int p2 = 0; p2 < 16; ++p2) zr += z_part[p2 * 128 + tid];
        float zt = fmaxf(zr, 0.f);
        p0 = zt * Wd2[tid * 2 + 0];
        p1 = zt * Wd2[tid * 2 + 1];
    }
    #pragma unroll
    for (int off = 32; off > 0; off >>= 1) {
        p0 += __shfl_down(p0, off, 64);
        p1 += __shfl_down(p1, off, 64);
    }
    if ((tid & 63) == 0) { sh[tid >> 6] = p0; sh[32 + (tid >> 6)] = p1; }
    __syncthreads();
    if (tid == 0) {
        float l0 = bd2[0], l1 = bd2[1];
        #pragma unroll
        for (int q = 0; q < 16; ++q) { l0 += sh[q]; l1 += sh[32 + q]; }
        float m = fmaxf(l0, l1);
        float e0 = expf(l0 - m), e1 = expf(l1 - m);
        float inv = 1.0f / (e0 + e1);
        out[0] = e0 * inv;
        out[1] = e1 * inv;
    }
}

extern "C" void kernel_launch(void* const* d_in, const int* in_sizes, int n_in,
                              void* d_out, int out_size, void* d_ws, size_t ws_size,
                              hipStream_t stream) {
    const float* x   = (const float*)d_in[0];
    const int*   ei  = (const int*)  d_in[1];
    const float* w   = (const float*)d_in[2];
    const float* W1  = (const float*)d_in[3];
    const float* b1  = (const float*)d_in[4];
    const float* W2  = (const float*)d_in[5];
    const float* b2  = (const float*)d_in[6];
    const float* Wd1 = (const float*)d_in[7];
    const float* bd1 = (const float*)d_in[8];
    const float* Wd2 = (const float*)d_in[9];
    const float* bd2 = (const float*)d_in[10];
    float* out = (float*)d_out;

    const int N = in_sizes[0] / D_IN;      // 20000
    const int E = in_sizes[1] / 2;         // 640000
    const int* row = ei;
    const int* col = ei + E;

    // workspace layout. Everything except ctr is written before read; ctr is
    // zeroed by scatter-0 (two kernel boundaries before k_tail reads it).
    unsigned* ctr = (unsigned*)d_ws;                       // 16 slots
    float* fws    = (float*)d_ws + 16;
    float* part   = fws;                                   // NSL*N = 2.56M
    float* dinv   = part + (size_t)NSL * N;                // N
    float* u      = dinv + N;                              // N
    float* s_part = u + N;                                 // NTILE*128
    float* S_u_p  = s_part + (size_t)NTILE * D_IN;         // NFOLD
    float* S_u_g  = S_u_p + NFOLD;                         // 1
    float* M      = S_u_g + 1;                             // 128*256
    float* c2     = M + D_IN * D_HID;                      // 256
    float* g_part = c2 + D_HID;                            // 16*256
    float* z_part = g_part + 16 * D_HID;                   // 16*128

    // pass 1: deg by col -> dinv; spare fold blocks compute M=W1@W2, c2=b1@W2
    k_scatter<<<2 * NSL, 1024, 0, stream>>>(col, row, w, dinv, u, part, ctr, E, N, 0);
    k_fold<<<NFOLD + 64, 1024, 0, stream>>>(part, dinv, u, S_u_p, W1, b1, W2, M, c2, N, 0);
    // pass 2: by row, gather dinv[col] -> u, S_u partials
    k_scatter<<<2 * NSL, 1024, 0, stream>>>(row, col, w, dinv, u, part, ctr, E, N, 1);
    k_fold<<<NFOLD, 1024, 0, stream>>>(part, dinv, u, S_u_p, W1, b1, W2, M, c2, N, 1);
    // pass 3: by row, gather dinv[col]*u[col] -> (folded inside k_tail)
    k_scatter<<<2 * NSL, 1024, 0, stream>>>(row, col, w, dinv, u, part, ctr, E, N, 2);
    // wv-fold + feature contraction + head (light device barriers inside)
    k_tail<<<256, 1024, 0, stream>>>(x, part, dinv, u, S_u_p, M, c2, b2,
                                     Wd1, bd1, Wd2, bd2, s_part, g_part, z_part,
                                     S_u_g, ctr, out, N, 1.0f / (float)N);
}